// Round 18
// baseline (452.232 us; speedup 1.0000x reference)
//
#include <hip/hip_runtime.h>

typedef unsigned short ushort_t;
typedef __attribute__((ext_vector_type(8))) short bf16x8;
typedef __attribute__((ext_vector_type(4))) float f32x4;
typedef __attribute__((ext_vector_type(4))) int int4v;

__device__ __forceinline__ unsigned short f2bf(float f){
  unsigned u = __float_as_uint(f);
  u = (u + 0x7FFFu + ((u >> 16) & 1u)) >> 16;     // round-to-nearest-even
  return (unsigned short)u;
}
__device__ __forceinline__ float bf2f(unsigned short h){
  return __uint_as_float(((unsigned)h) << 16);
}

// ---------------- CSR build (bucket-local) ----------------

// Histogram over buckets (dst>>8) + inline exclusive scan by the last block
// (ticket pattern; bcnt read back via atomicAdd(,0) for cross-XCD coherence).
__global__ __launch_bounds__(256) void k_bhist(const int* __restrict__ dst, int* __restrict__ bcnt,
                                               int* __restrict__ ticket,
                                               int* __restrict__ bbase, int* __restrict__ bcur,
                                               int* __restrict__ rp,
                                               int E, int NB, int N, int nblk){
  __shared__ int l[512];
  __shared__ int sA[512];
  __shared__ int sB[512];
  __shared__ int isLast;
  int t = threadIdx.x;
  for(int b=t; b<512; b+=256) l[b] = 0;
  __syncthreads();
  int base = blockIdx.x*4096 + t*16;
  if(base + 16 <= E){
    #pragma unroll
    for(int r=0;r<4;++r){
      int4v d = __builtin_nontemporal_load((const int4v*)(dst + base + r*4));
      atomicAdd(&l[d.x >> 8], 1); atomicAdd(&l[d.y >> 8], 1);
      atomicAdd(&l[d.z >> 8], 1); atomicAdd(&l[d.w >> 8], 1);
    }
  } else {
    for(int i=base; i<E; ++i) atomicAdd(&l[dst[i] >> 8], 1);
  }
  __syncthreads();
  for(int b=t; b<NB; b+=256){
    int c = l[b];
    if(c) atomicAdd(&bcnt[b], c);
  }
  __threadfence();
  if(t == 0) isLast = (atomicAdd(ticket, 1) == nblk - 1);
  __syncthreads();
  if(!isLast) return;

  // ---- last block: exclusive scan of bcnt[0..NB) ----
  int orig[2];
  for(int r=0;r<2;++r){
    int i = r*256 + t;
    orig[r] = (i < NB) ? atomicAdd(&bcnt[i], 0) : 0;   // coherent read
    sA[i] = orig[r];
  }
  __syncthreads();
  int* cur = sA; int* nxt = sB;
  for(int off=1; off<512; off<<=1){
    for(int r=0;r<2;++r){
      int i = r*256 + t;
      nxt[i] = (i >= off) ? cur[i] + cur[i-off] : cur[i];
    }
    __syncthreads();
    int* tmp = cur; cur = nxt; nxt = tmp;
  }
  for(int r=0;r<2;++r){
    int i = r*256 + t;
    if(i < NB){
      int excl = cur[i] - orig[r];
      bbase[i] = excl;
      bcur[i]  = excl;
      if(i == NB-1) bbase[NB] = excl + orig[r];   // = E
    }
  }
  if(t == 0) rp[N] = E;
}

__global__ __launch_bounds__(256) void k_part(const int* __restrict__ src, const int* __restrict__ dst,
                                              int* __restrict__ bcur, unsigned* __restrict__ ebuf,
                                              int E, int NB){
  __shared__ int lcnt[512];
  __shared__ int lbase[512];
  int t = threadIdx.x;
  int base = blockIdx.x*4096 + t*16;
  for(int b=t; b<NB; b+=256) lcnt[b] = 0;
  __syncthreads();

  int srcv[16], dstv[16];
  if(base + 16 <= E){
    #pragma unroll
    for(int r=0;r<4;++r){
      *(int4v*)(dstv + r*4) = __builtin_nontemporal_load((const int4v*)(dst + base + r*4));
      *(int4v*)(srcv + r*4) = __builtin_nontemporal_load((const int4v*)(src + base + r*4));
    }
  } else {
    #pragma unroll
    for(int k=0;k<16;++k){
      int i = base + k;
      if(i < E){ dstv[k] = dst[i]; srcv[k] = src[i]; }
      else dstv[k] = -1;
    }
  }
  #pragma unroll
  for(int r=0;r<16;++r)
    if(dstv[r] >= 0) atomicAdd(&lcnt[dstv[r] >> 8], 1);
  __syncthreads();
  for(int b=t; b<NB; b+=256){
    int c = lcnt[b];
    lbase[b] = c ? atomicAdd(&bcur[b], c) : 0;
    lcnt[b] = 0;
  }
  __syncthreads();
  #pragma unroll
  for(int r=0;r<16;++r){
    if(dstv[r] >= 0){
      int b = dstv[r] >> 8;
      int p = lbase[b] + atomicAdd(&lcnt[b], 1);
      ebuf[p] = (((unsigned)dstv[r] & 255u) << 17) | (unsigned)srcv[r];
    }
  }
}

__global__ __launch_bounds__(256) void k_place(const int* __restrict__ bbase, const unsigned* __restrict__ ebuf,
                                               int* __restrict__ esrc, int* __restrict__ rp, int N){
  __shared__ int lcnt[256];
  __shared__ int sc[256];
  __shared__ int lcur[256];
  int t = threadIdx.x;
  int b = blockIdx.x;
  int n0 = b << 8;
  int e0 = bbase[b], e1 = bbase[b+1];
  lcnt[t] = 0;
  __syncthreads();
  for(int i = e0 + t; i < e1; i += 256)
    atomicAdd(&lcnt[ebuf[i] >> 17], 1);
  __syncthreads();
  int v = lcnt[t];
  sc[t] = v;
  __syncthreads();
  for(int off=1; off<256; off<<=1){
    int x = 0;
    if(t >= off) x = sc[t-off];
    __syncthreads();
    if(t >= off) sc[t] += x;
    __syncthreads();
  }
  int rpv = e0 + sc[t] - v;
  if(n0 + t < N) rp[n0 + t] = rpv;
  lcur[t] = rpv;
  __syncthreads();
  for(int i = e0 + t; i < e1; i += 256){
    unsigned w = ebuf[i];
    int dl = (int)(w >> 17);
    int p = atomicAdd(&lcur[dl], 1);
    esrc[p] = (int)(w & 0x1FFFFu);
  }
}

// ---------------- init: weight transpose+cast (blocks 0..191) + proj (rest) ----------------
__global__ __launch_bounds__(256) void k_init(const float* __restrict__ w1a, const float* __restrict__ w2a,
                                              const float* __restrict__ w1b, const float* __restrict__ w2b,
                                              const float* __restrict__ w1c, const float* __restrict__ w2c,
                                              ushort_t* __restrict__ w1t, ushort_t* __restrict__ w2t,
                                              const float* __restrict__ x,
                                              const float* __restrict__ ws, const float* __restrict__ bs,
                                              const float* __restrict__ wd, const float* __restrict__ bd,
                                              ushort_t* __restrict__ hd16, ushort_t* __restrict__ gs16, int N){
  if(blockIdx.x < 192){
    int L = blockIdx.x >> 6;
    const float* w1 = (L==0) ? w1a : (L==1) ? w1b : w1c;
    const float* w2 = (L==0) ? w2a : (L==1) ? w2b : w2c;
    int t = (blockIdx.x & 63)*256 + threadIdx.x;
    if(t < 8192){
      int n = t >> 6, k = t & 63;
      w1t[L*8192 + n*64 + k] = f2bf(w1[k*128 + n]);
    } else {
      int i = t - 8192;
      int n = i >> 7, k = i & 127;
      w2t[L*8192 + n*128 + k] = f2bf(w2[k*64 + n]);
    }
    return;
  }
  int gid = (blockIdx.x - 192)*256 + threadIdx.x;
  int n = gid >> 6, c = gid & 63;
  if(n >= N) return;
  float as = bs[c], ad = bd[c];
  const float* xr = x + (size_t)n*9;
  #pragma unroll
  for(int k=0;k<9;++k){
    float xv = xr[k];
    as += xv * ws[k*64 + c];
    ad += xv * wd[k*64 + c];
  }
  hd16[(size_t)n*64 + c] = f2bf(ad);
  gs16[(size_t)n*64 + c] = f2bf(fmaxf(as, 0.f));
}

// ---------------- fused edge + MLP1: h1 = (softmax-agg + xd) @ w1 + b1 ----------------
// Eps-folding (exact): exp(v+eps) = e^eps * exp(v); the constant cancels in the
// softmax ratio, so S += exp(v), T += exp(v)*v, aggr = (T + eps*S)/(S + 1e-16).
// deg==0 -> 0. BN col partials -> fp32 atomics into this layer's bnp slice
// keyed blockIdx&31 (8192 addresses).
__global__ __launch_bounds__(256) void k_emlp1(const ushort_t* __restrict__ gs, const ushort_t* __restrict__ xd16,
                                               const int* __restrict__ rp, const int* __restrict__ es,
                                               const ushort_t* __restrict__ w1t, const float* __restrict__ b1,
                                               ushort_t* __restrict__ h1, float* __restrict__ bnp, int N){
  __shared__ ushort_t yt[32*72];       // y tile
  __shared__ ushort_t cs[32*136];      // C staging
  int t = threadIdx.x;
  int w = t >> 6, lane = t & 63;
  int nbase = blockIdx.x * 32;

  // ---- edge phase: wave w aggregates nodes nbase + w*8 .. +7 ----
  const ushort_t* gl = gs + lane;
  for(int i=0;i<8;++i){
    int nl = w*8 + i;
    int n = nbase + nl;
    float aggr = 0.f;
    if(n < N){
      int beg = __builtin_amdgcn_readfirstlane(rp[n]);
      int end = __builtin_amdgcn_readfirstlane(rp[n+1]);
      float S[8], T[8];
      #pragma unroll
      for(int j=0;j<8;++j){ S[j]=0.f; T[j]=0.f; }
      int nfull = beg + ((end - beg) & ~7);
      int base = beg;
      for(; base < nfull; base += 8){       // interior: no per-element mask
        float g[8];
        #pragma unroll
        for(int j=0;j<8;++j){
          int idx = __builtin_amdgcn_readfirstlane(es[base+j]);
          g[j] = bf2f(gl[(size_t)idx*64]);
        }
        #pragma unroll
        for(int j=0;j<8;++j){
          float p = __expf(g[j]);
          S[j] += p; T[j] += p*g[j];
        }
      }
      if(base < end){                        // single masked tail group
        float g[8];
        #pragma unroll
        for(int j=0;j<8;++j){
          int e = base + j;
          int idx = __builtin_amdgcn_readfirstlane(es[e < end ? e : end-1]);
          g[j] = bf2f(gl[(size_t)idx*64]);
        }
        #pragma unroll
        for(int j=0;j<8;++j){
          float p = (base + j < end) ? __expf(g[j]) : 0.f;
          S[j] += p; T[j] += p*g[j];
        }
      }
      float Ss = ((S[0]+S[1])+(S[2]+S[3])) + ((S[4]+S[5])+(S[6]+S[7]));
      float Ts = ((T[0]+T[1])+(T[2]+T[3])) + ((T[4]+T[5])+(T[6]+T[7]));
      aggr = (Ts + 1e-7f*Ss)/(Ss + 1e-16f) + bf2f(xd16[(size_t)n*64 + lane]);
    }
    yt[nl*72 + lane] = f2bf(aggr);
  }
  __syncthreads();

  // ---- MFMA phase (mlp1): A from LDS y-tile ----
  int ln = lane & 15, quad = lane >> 4;
  bf16x8 B[2][2];
  #pragma unroll
  for(int c=0;c<2;++c){
    int n = (2*w+c)*16 + ln;
    #pragma unroll
    for(int q=0;q<2;++q)
      B[c][q] = *(const bf16x8*)(w1t + n*64 + q*32 + quad*8);
  }

  f32x4 z = {0.f,0.f,0.f,0.f};
  f32x4 acc[2][2] = {{z,z},{z,z}};
  #pragma unroll
  for(int q=0;q<2;++q){
    #pragma unroll
    for(int tt=0;tt<2;++tt){
      bf16x8 A = *(const bf16x8*)(yt + (tt*16 + ln)*72 + q*32 + quad*8);
      #pragma unroll
      for(int c=0;c<2;++c)
        acc[tt][c] = __builtin_amdgcn_mfma_f32_16x16x32_bf16(A, B[c][q], acc[tt][c], 0,0,0);
    }
  }

  float s[2] = {0.f, 0.f}, qq[2] = {0.f, 0.f};
  #pragma unroll
  for(int c=0;c<2;++c){
    int n = (2*w+c)*16 + ln;
    float bb = b1[n];
    #pragma unroll
    for(int tt=0;tt<2;++tt){
      #pragma unroll
      for(int r=0;r<4;++r){
        int row = tt*16 + quad*4 + r;
        float v = acc[tt][c][r] + bb;
        bool ok = (nbase + row) < N;
        s[c]  += ok ? v   : 0.f;
        qq[c] += ok ? v*v : 0.f;
        cs[row*136 + n] = f2bf(v);
      }
    }
  }
  {
    float* slice = bnp + (size_t)(blockIdx.x & 31)*256;
    #pragma unroll
    for(int c=0;c<2;++c){
      float vs = s[c], vq = qq[c];
      vs += __shfl_down(vs, 32, 64); vs += __shfl_down(vs, 16, 64);
      vq += __shfl_down(vq, 32, 64); vq += __shfl_down(vq, 16, 64);
      if(quad == 0){
        int col = (2*w+c)*16 + ln;
        atomicAdd(&slice[col], vs);
        atomicAdd(&slice[128+col], vq);
      }
    }
  }
  __syncthreads();
  #pragma unroll
  for(int r2=0;r2<2;++r2){
    int idx = r2*256 + t;
    int row = idx >> 4, c8 = (idx & 15)*8;
    int m = nbase + row;
    if(m < N)
      *(uint4*)(h1 + (size_t)m*128 + c8) = *(const uint4*)(cs + row*136 + c8);
  }
}

// ---------------- MLP part 2 (MFMA) + inline BN fold ----------------
// Each block redundantly folds this layer's bnp[32][256] slice (L2-hot 32KB)
// into LDS scale/bias, then h16 = relu(relu(bn(h1)) @ w2 + b2).
__global__ __launch_bounds__(256) void k_mlp2(const ushort_t* __restrict__ h1, const float* __restrict__ bnp,
                                              const float* __restrict__ g, const float* __restrict__ be,
                                              const ushort_t* __restrict__ w2t, const float* __restrict__ b2,
                                              ushort_t* __restrict__ h16, float invN, int N){
  __shared__ float sbl[256];
  __shared__ ushort_t act[64*136];
  __shared__ ushort_t cs2[64*72];
  int t = threadIdx.x;
  if(t < 128){
    float s = 0.f, q = 0.f;
    #pragma unroll 4
    for(int b=0;b<32;++b){ s += bnp[b*256 + t]; q += bnp[b*256 + 128 + t]; }
    float mu = s*invN;
    float var = q*invN - mu*mu;
    float sc = g[t] * rsqrtf(var + 1e-5f);
    sbl[t] = sc;
    sbl[128+t] = be[t] - mu*sc;
  }
  __syncthreads();
  int n0 = blockIdx.x*64;
  #pragma unroll
  for(int r=0;r<4;++r){
    int idx = r*256 + t;
    int row = idx >> 4, k8 = (idx & 15)*8;
    int n = n0 + row;
    ushort_t tmp[8];
    if(n < N){
      *(uint4*)tmp = *(const uint4*)(h1 + (size_t)n*128 + k8);
    } else {
      #pragma unroll
      for(int j=0;j<8;++j) tmp[j] = 0;
    }
    #pragma unroll
    for(int j=0;j<8;++j){
      float v = bf2f(tmp[j]) * sbl[k8+j] + sbl[128+k8+j];
      tmp[j] = f2bf(fmaxf(v, 0.f));
    }
    *(uint4*)(act + row*136 + k8) = *(uint4*)tmp;
  }
  __syncthreads();
  int w = t >> 6, lane = t & 63;
  int ln = lane & 15, quad = lane >> 4;

  int n = w*16 + ln;
  bf16x8 B[4];
  #pragma unroll
  for(int q=0;q<4;++q)
    B[q] = *(const bf16x8*)(w2t + n*128 + q*32 + quad*8);

  f32x4 z = {0.f,0.f,0.f,0.f};
  f32x4 acc[4] = {z,z,z,z};
  #pragma unroll
  for(int q=0;q<4;++q){
    #pragma unroll
    for(int tt=0;tt<4;++tt){
      bf16x8 A = *(const bf16x8*)(act + (tt*16 + ln)*136 + q*32 + quad*8);
      acc[tt] = __builtin_amdgcn_mfma_f32_16x16x32_bf16(A, B[q], acc[tt], 0,0,0);
    }
  }
  float bb = b2[n];
  #pragma unroll
  for(int tt=0;tt<4;++tt){
    #pragma unroll
    for(int r=0;r<4;++r){
      int row = tt*16 + quad*4 + r;
      float v = fmaxf(acc[tt][r] + bb, 0.f);
      cs2[row*72 + n] = f2bf(v);
    }
  }
  __syncthreads();
  #pragma unroll
  for(int r2=0;r2<2;++r2){
    int idx = r2*256 + t;
    int row = idx >> 3, c8 = (idx & 7)*8;
    int m = n0 + row;
    if(m < N)
      *(uint4*)(h16 + (size_t)m*64 + c8) = *(const uint4*)(cs2 + row*72 + c8);
  }
}

// ---------------- fused mean-pool + dense + sigmoid (bf16 input) ----------------
__device__ __forceinline__ int lbound(const int* a, int n, int key){
  int lo = 0, hi = n;
  while(lo < hi){
    int mid = (lo + hi) >> 1;
    if(a[mid] < key) lo = mid + 1; else hi = mid;
  }
  return lo;
}

__global__ __launch_bounds__(256) void k_pool(const ushort_t* __restrict__ h16, const int* __restrict__ batch,
                                              const float* __restrict__ wd, const float* __restrict__ bd,
                                              float* __restrict__ out, int N){
  int g = blockIdx.x;
  int lo = lbound(batch, N, g);
  int hi = lbound(batch, N, g+1);
  int c = threadIdx.x & 63, w = threadIdx.x >> 6;
  float acc = 0.f;
  for(int n = lo + w; n < hi; n += 4) acc += bf2f(h16[(size_t)n*64 + c]);
  __shared__ float red[4][64];
  red[w][c] = acc;
  __syncthreads();
  if(w == 0){
    float v = red[0][c] + red[1][c] + red[2][c] + red[3][c];
    float count = (float)(hi - lo);
    v = v / fmaxf(count, 1.f) * wd[c];
    for(int off=32; off>0; off>>=1) v += __shfl_down(v, off, 64);
    if(c == 0) out[g] = 1.f / (1.f + expf(-(v + bd[0])));
  }
}

// ---------------- host ----------------

extern "C" void kernel_launch(void* const* d_in, const int* in_sizes, int n_in,
                              void* d_out, int out_size, void* d_ws, size_t ws_size,
                              hipStream_t stream){
  const float* x      = (const float*)d_in[0];
  const int*   ei     = (const int*)  d_in[1];
  const int*   batch  = (const int*)  d_in[2];
  const float* w_src  = (const float*)d_in[3];
  const float* b_src  = (const float*)d_in[4];
  const float* w_dst  = (const float*)d_in[5];
  const float* b_dst  = (const float*)d_in[6];
  const float* w_dense= (const float*)d_in[25];
  const float* b_dense= (const float*)d_in[26];
  float* out = (float*)d_out;

  const int N = in_sizes[2];
  const int E = in_sizes[1] / 2;
  const int* src = ei;
  const int* dst = ei + E;

  char* ws = (char*)d_ws;
  size_t off = 0;
  auto take = [&](size_t bytes) -> void* {
    void* p = ws + off;
    off += (bytes + 255) & ~(size_t)255;
    return p;
  };
  ushort_t* hd16 = (ushort_t*)take((size_t)N*64*2);
  ushort_t* gs16 = (ushort_t*)take((size_t)N*64*2);
  ushort_t* h1   = (ushort_t*)take((size_t)N*128*2);
  ushort_t* h16  = (ushort_t*)take((size_t)N*64*2);
  unsigned* ebuf = (unsigned*)take((size_t)E*4);
  int*      esrc = (int*)     take((size_t)E*4);
  int*      rp   = (int*)     take((size_t)(N+1)*4);
  // zero-region: bcnt[512] + ticket[64] + bnp[3*8192]  (one memset)
  int*      bcnt = (int*)     take(512*4 + 64*4 + 3*32*256*4);
  int*      ticket = bcnt + 512;
  float*    bnp  = (float*)(ticket + 64);
  int*      bbase= (int*)     take(520*4);
  int*      bcur = (int*)     take(512*4);
  ushort_t* w1t  = (ushort_t*)take(3*8192*2);
  ushort_t* w2t  = (ushort_t*)take(3*8192*2);

  const int nblk1 = (N + 31) / 32;
  const int gN64  = (N*64 + 255) / 256;
  const int NB    = (N + 255) >> 8;
  const int nchnk = (E + 4095) / 4096;
  const size_t zbytes = 512*4 + 64*4 + 3*32*256*4;

  (void)hipMemsetAsync(bcnt, 0, zbytes, stream);

  // ---- CSR by dst (bucket-local; bhist has inline last-block scan) ----
  k_bhist<<<nchnk, 256, 0, stream>>>(dst, bcnt, ticket, bbase, bcur, rp, E, NB, N, nchnk);
  k_part <<<nchnk, 256, 0, stream>>>(src, dst, bcur, ebuf, E, NB);
  k_place<<<NB,    256, 0, stream>>>(bbase, ebuf, esrc, rp, N);

  // ---- weight transpose+cast + layer-1 projections, one launch ----
  k_init<<<192 + gN64, 256, 0, stream>>>(
    (const float*)d_in[7],  (const float*)d_in[11],
    (const float*)d_in[13], (const float*)d_in[17],
    (const float*)d_in[19], (const float*)d_in[23],
    w1t, w2t,
    x, w_src, b_src, w_dst, b_dst, hd16, gs16, N);

  // ---- 3 conv layers (layers 2/3: gather source == residual == h16) ----
  const ushort_t* gs_l[3] = { gs16, h16, h16 };
  const ushort_t* xd_l[3] = { hd16, h16, h16 };
  const float invN = 1.0f / (float)N;

  for(int L=0; L<3; ++L){
    const float* b1 = (const float*)d_in[7 + 6*L + 1];
    const float* g  = (const float*)d_in[7 + 6*L + 2];
    const float* be = (const float*)d_in[7 + 6*L + 3];
    const float* b2 = (const float*)d_in[7 + 6*L + 5];
    float* bnpL = bnp + (size_t)L*32*256;

    k_emlp1<<<nblk1, 256, 0, stream>>>(gs_l[L], xd_l[L], rp, esrc, w1t + L*8192, b1, h1, bnpL, N);
    k_mlp2<<<(N+63)/64, 256, 0, stream>>>(h1, bnpL, g, be, w2t + L*8192, b2, h16, invN, N);
  }

  // ---- pooled dense + sigmoid ----
  k_pool<<<512, 256, 0, stream>>>(h16, batch, w_dense, b_dense, out, N);
}

// Round 19
// 447.667 us; speedup vs baseline: 1.0102x; 1.0102x over previous
//
#include <hip/hip_runtime.h>

typedef unsigned short ushort_t;
typedef __attribute__((ext_vector_type(8))) short bf16x8;
typedef __attribute__((ext_vector_type(4))) float f32x4;
typedef __attribute__((ext_vector_type(4))) int int4v;

__device__ __forceinline__ unsigned short f2bf(float f){
  unsigned u = __float_as_uint(f);
  u = (u + 0x7FFFu + ((u >> 16) & 1u)) >> 16;     // round-to-nearest-even
  return (unsigned short)u;
}
__device__ __forceinline__ float bf2f(unsigned short h){
  return __uint_as_float(((unsigned)h) << 16);
}

// ---------------- CSR build (bucket-local) ----------------

// Histogram over buckets (dst>>8) + inline exclusive scan by the last block
// (ticket pattern; bcnt read back via atomicAdd(,0) for cross-XCD coherence).
__global__ __launch_bounds__(256) void k_bhist(const int* __restrict__ dst, int* __restrict__ bcnt,
                                               int* __restrict__ ticket,
                                               int* __restrict__ bbase, int* __restrict__ bcur,
                                               int* __restrict__ rp,
                                               int E, int NB, int N, int nblk){
  __shared__ int l[512];
  __shared__ int sA[512];
  __shared__ int sB[512];
  __shared__ int isLast;
  int t = threadIdx.x;
  for(int b=t; b<512; b+=256) l[b] = 0;
  __syncthreads();
  int base = blockIdx.x*4096 + t*16;
  if(base + 16 <= E){
    #pragma unroll
    for(int r=0;r<4;++r){
      int4v d = __builtin_nontemporal_load((const int4v*)(dst + base + r*4));
      atomicAdd(&l[d.x >> 8], 1); atomicAdd(&l[d.y >> 8], 1);
      atomicAdd(&l[d.z >> 8], 1); atomicAdd(&l[d.w >> 8], 1);
    }
  } else {
    for(int i=base; i<E; ++i) atomicAdd(&l[dst[i] >> 8], 1);
  }
  __syncthreads();
  for(int b=t; b<NB; b+=256){
    int c = l[b];
    if(c) atomicAdd(&bcnt[b], c);
  }
  __threadfence();
  if(t == 0) isLast = (atomicAdd(ticket, 1) == nblk - 1);
  __syncthreads();
  if(!isLast) return;

  // ---- last block: exclusive scan of bcnt[0..NB) ----
  int orig[2];
  for(int r=0;r<2;++r){
    int i = r*256 + t;
    orig[r] = (i < NB) ? atomicAdd(&bcnt[i], 0) : 0;   // coherent read
    sA[i] = orig[r];
  }
  __syncthreads();
  int* cur = sA; int* nxt = sB;
  for(int off=1; off<512; off<<=1){
    for(int r=0;r<2;++r){
      int i = r*256 + t;
      nxt[i] = (i >= off) ? cur[i] + cur[i-off] : cur[i];
    }
    __syncthreads();
    int* tmp = cur; cur = nxt; nxt = tmp;
  }
  for(int r=0;r<2;++r){
    int i = r*256 + t;
    if(i < NB){
      int excl = cur[i] - orig[r];
      bbase[i] = excl;
      bcur[i]  = excl;
      if(i == NB-1) bbase[NB] = excl + orig[r];   // = E
    }
  }
  if(t == 0) rp[N] = E;
}

__global__ __launch_bounds__(256) void k_part(const int* __restrict__ src, const int* __restrict__ dst,
                                              int* __restrict__ bcur, unsigned* __restrict__ ebuf,
                                              int E, int NB){
  __shared__ int lcnt[512];
  __shared__ int lbase[512];
  int t = threadIdx.x;
  int base = blockIdx.x*4096 + t*16;
  for(int b=t; b<NB; b+=256) lcnt[b] = 0;
  __syncthreads();

  int srcv[16], dstv[16];
  if(base + 16 <= E){
    #pragma unroll
    for(int r=0;r<4;++r){
      *(int4v*)(dstv + r*4) = __builtin_nontemporal_load((const int4v*)(dst + base + r*4));
      *(int4v*)(srcv + r*4) = __builtin_nontemporal_load((const int4v*)(src + base + r*4));
    }
  } else {
    #pragma unroll
    for(int k=0;k<16;++k){
      int i = base + k;
      if(i < E){ dstv[k] = dst[i]; srcv[k] = src[i]; }
      else dstv[k] = -1;
    }
  }
  #pragma unroll
  for(int r=0;r<16;++r)
    if(dstv[r] >= 0) atomicAdd(&lcnt[dstv[r] >> 8], 1);
  __syncthreads();
  for(int b=t; b<NB; b+=256){
    int c = lcnt[b];
    lbase[b] = c ? atomicAdd(&bcur[b], c) : 0;
    lcnt[b] = 0;
  }
  __syncthreads();
  #pragma unroll
  for(int r=0;r<16;++r){
    if(dstv[r] >= 0){
      int b = dstv[r] >> 8;
      int p = lbase[b] + atomicAdd(&lcnt[b], 1);
      ebuf[p] = (((unsigned)dstv[r] & 255u) << 17) | (unsigned)srcv[r];
    }
  }
}

__global__ __launch_bounds__(256) void k_place(const int* __restrict__ bbase, const unsigned* __restrict__ ebuf,
                                               int* __restrict__ esrc, int* __restrict__ rp, int N){
  __shared__ int lcnt[256];
  __shared__ int sc[256];
  __shared__ int lcur[256];
  int t = threadIdx.x;
  int b = blockIdx.x;
  int n0 = b << 8;
  int e0 = bbase[b], e1 = bbase[b+1];
  lcnt[t] = 0;
  __syncthreads();
  for(int i = e0 + t; i < e1; i += 256)
    atomicAdd(&lcnt[ebuf[i] >> 17], 1);
  __syncthreads();
  int v = lcnt[t];
  sc[t] = v;
  __syncthreads();
  for(int off=1; off<256; off<<=1){
    int x = 0;
    if(t >= off) x = sc[t-off];
    __syncthreads();
    if(t >= off) sc[t] += x;
    __syncthreads();
  }
  int rpv = e0 + sc[t] - v;
  if(n0 + t < N) rp[n0 + t] = rpv;
  lcur[t] = rpv;
  __syncthreads();
  for(int i = e0 + t; i < e1; i += 256){
    unsigned w = ebuf[i];
    int dl = (int)(w >> 17);
    int p = atomicAdd(&lcur[dl], 1);
    esrc[p] = (int)(w & 0x1FFFFu);
  }
}

// ---------------- init: weight transpose+cast (blocks 0..191) + proj (rest) ----------------
__global__ __launch_bounds__(256) void k_init(const float* __restrict__ w1a, const float* __restrict__ w2a,
                                              const float* __restrict__ w1b, const float* __restrict__ w2b,
                                              const float* __restrict__ w1c, const float* __restrict__ w2c,
                                              ushort_t* __restrict__ w1t, ushort_t* __restrict__ w2t,
                                              const float* __restrict__ x,
                                              const float* __restrict__ ws, const float* __restrict__ bs,
                                              const float* __restrict__ wd, const float* __restrict__ bd,
                                              ushort_t* __restrict__ hd16, ushort_t* __restrict__ gs16, int N){
  if(blockIdx.x < 192){
    int L = blockIdx.x >> 6;
    const float* w1 = (L==0) ? w1a : (L==1) ? w1b : w1c;
    const float* w2 = (L==0) ? w2a : (L==1) ? w2b : w2c;
    int t = (blockIdx.x & 63)*256 + threadIdx.x;
    if(t < 8192){
      int n = t >> 6, k = t & 63;
      w1t[L*8192 + n*64 + k] = f2bf(w1[k*128 + n]);
    } else {
      int i = t - 8192;
      int n = i >> 7, k = i & 127;
      w2t[L*8192 + n*128 + k] = f2bf(w2[k*64 + n]);
    }
    return;
  }
  int gid = (blockIdx.x - 192)*256 + threadIdx.x;
  int n = gid >> 6, c = gid & 63;
  if(n >= N) return;
  float as = bs[c], ad = bd[c];
  const float* xr = x + (size_t)n*9;
  #pragma unroll
  for(int k=0;k<9;++k){
    float xv = xr[k];
    as += xv * ws[k*64 + c];
    ad += xv * wd[k*64 + c];
  }
  hd16[(size_t)n*64 + c] = f2bf(ad);
  gs16[(size_t)n*64 + c] = f2bf(fmaxf(as, 0.f));
}

// ---------------- fused edge + MLP1: h1 = (softmax-agg + xd) @ w1 + b1 ----------------
// Eps-folding (exact): exp(v+eps) = e^eps * exp(v); the constant cancels in the
// softmax ratio, so S += exp(v), T += exp(v)*v, aggr = (T + eps*S)/(S + 1e-16).
__global__ __launch_bounds__(256) void k_emlp1(const ushort_t* __restrict__ gs, const ushort_t* __restrict__ xd16,
                                               const int* __restrict__ rp, const int* __restrict__ es,
                                               const ushort_t* __restrict__ w1t, const float* __restrict__ b1,
                                               ushort_t* __restrict__ h1, float* __restrict__ bnp, int N){
  __shared__ ushort_t yt[32*72];       // y tile
  __shared__ ushort_t cs[32*136];      // C staging
  int t = threadIdx.x;
  int w = t >> 6, lane = t & 63;
  int nbase = blockIdx.x * 32;

  // ---- edge phase: wave w aggregates nodes nbase + w*8 .. +7 ----
  const ushort_t* gl = gs + lane;
  for(int i=0;i<8;++i){
    int nl = w*8 + i;
    int n = nbase + nl;
    float aggr = 0.f;
    if(n < N){
      int beg = __builtin_amdgcn_readfirstlane(rp[n]);
      int end = __builtin_amdgcn_readfirstlane(rp[n+1]);
      float S[8], T[8];
      #pragma unroll
      for(int j=0;j<8;++j){ S[j]=0.f; T[j]=0.f; }
      int nfull = beg + ((end - beg) & ~7);
      int base = beg;
      for(; base < nfull; base += 8){       // interior: no per-element mask
        float g[8];
        #pragma unroll
        for(int j=0;j<8;++j){
          int idx = __builtin_amdgcn_readfirstlane(es[base+j]);
          g[j] = bf2f(gl[(size_t)idx*64]);
        }
        #pragma unroll
        for(int j=0;j<8;++j){
          float p = __expf(g[j]);
          S[j] += p; T[j] += p*g[j];
        }
      }
      if(base < end){                        // single masked tail group
        float g[8];
        #pragma unroll
        for(int j=0;j<8;++j){
          int e = base + j;
          int idx = __builtin_amdgcn_readfirstlane(es[e < end ? e : end-1]);
          g[j] = bf2f(gl[(size_t)idx*64]);
        }
        #pragma unroll
        for(int j=0;j<8;++j){
          float p = (base + j < end) ? __expf(g[j]) : 0.f;
          S[j] += p; T[j] += p*g[j];
        }
      }
      float Ss = ((S[0]+S[1])+(S[2]+S[3])) + ((S[4]+S[5])+(S[6]+S[7]));
      float Ts = ((T[0]+T[1])+(T[2]+T[3])) + ((T[4]+T[5])+(T[6]+T[7]));
      aggr = (Ts + 1e-7f*Ss)/(Ss + 1e-16f) + bf2f(xd16[(size_t)n*64 + lane]);
    }
    yt[nl*72 + lane] = f2bf(aggr);
  }
  __syncthreads();

  // ---- MFMA phase (mlp1): A from LDS y-tile ----
  int ln = lane & 15, quad = lane >> 4;
  bf16x8 B[2][2];
  #pragma unroll
  for(int c=0;c<2;++c){
    int n = (2*w+c)*16 + ln;
    #pragma unroll
    for(int q=0;q<2;++q)
      B[c][q] = *(const bf16x8*)(w1t + n*64 + q*32 + quad*8);
  }

  f32x4 z = {0.f,0.f,0.f,0.f};
  f32x4 acc[2][2] = {{z,z},{z,z}};
  #pragma unroll
  for(int q=0;q<2;++q){
    #pragma unroll
    for(int tt=0;tt<2;++tt){
      bf16x8 A = *(const bf16x8*)(yt + (tt*16 + ln)*72 + q*32 + quad*8);
      #pragma unroll
      for(int c=0;c<2;++c)
        acc[tt][c] = __builtin_amdgcn_mfma_f32_16x16x32_bf16(A, B[c][q], acc[tt][c], 0,0,0);
    }
  }

  float s[2] = {0.f, 0.f}, qq[2] = {0.f, 0.f};
  #pragma unroll
  for(int c=0;c<2;++c){
    int n = (2*w+c)*16 + ln;
    float bb = b1[n];
    #pragma unroll
    for(int tt=0;tt<2;++tt){
      #pragma unroll
      for(int r=0;r<4;++r){
        int row = tt*16 + quad*4 + r;
        float v = acc[tt][c][r] + bb;
        bool ok = (nbase + row) < N;
        s[c]  += ok ? v   : 0.f;
        qq[c] += ok ? v*v : 0.f;
        cs[row*136 + n] = f2bf(v);
      }
    }
  }
  {
    float* slice = bnp + (size_t)(blockIdx.x & 31)*256;
    #pragma unroll
    for(int c=0;c<2;++c){
      float vs = s[c], vq = qq[c];
      vs += __shfl_down(vs, 32, 64); vs += __shfl_down(vs, 16, 64);
      vq += __shfl_down(vq, 32, 64); vq += __shfl_down(vq, 16, 64);
      if(quad == 0){
        int col = (2*w+c)*16 + ln;
        atomicAdd(&slice[col], vs);
        atomicAdd(&slice[128+col], vq);
      }
    }
  }
  __syncthreads();
  #pragma unroll
  for(int r2=0;r2<2;++r2){
    int idx = r2*256 + t;
    int row = idx >> 4, c8 = (idx & 15)*8;
    int m = nbase + row;
    if(m < N)
      *(uint4*)(h1 + (size_t)m*128 + c8) = *(const uint4*)(cs + row*136 + c8);
  }
}

// fold BN stats from this layer's bnp[32][256] slice -> sb (scale/bias)
__global__ __launch_bounds__(128) void k_bnfold(const float* __restrict__ bnp, const float* __restrict__ g,
                                                const float* __restrict__ be, float* __restrict__ sb, float invN){
  int j = threadIdx.x;
  float s = 0.f, q = 0.f;
  for(int b=0;b<32;++b){ s += bnp[b*256 + j]; q += bnp[b*256 + 128 + j]; }
  float mu = s*invN;
  float var = q*invN - mu*mu;
  float sc = g[j] * rsqrtf(var + 1e-5f);
  sb[j] = sc;
  sb[128+j] = be[j] - mu*sc;
}

// ---------------- MLP part 2 (MFMA): h16 = relu(relu(bn(h1)) @ w2 + b2) ----------------
__global__ __launch_bounds__(256) void k_mlp2(const ushort_t* __restrict__ h1, const float* __restrict__ sb,
                                              const ushort_t* __restrict__ w2t, const float* __restrict__ b2,
                                              ushort_t* __restrict__ h16, int N){
  __shared__ ushort_t act[64*136];
  __shared__ ushort_t cs2[64*72];
  int t = threadIdx.x;
  int n0 = blockIdx.x*64;
  #pragma unroll
  for(int r=0;r<4;++r){
    int idx = r*256 + t;
    int row = idx >> 4, k8 = (idx & 15)*8;
    int n = n0 + row;
    ushort_t tmp[8];
    if(n < N){
      *(uint4*)tmp = *(const uint4*)(h1 + (size_t)n*128 + k8);
    } else {
      #pragma unroll
      for(int j=0;j<8;++j) tmp[j] = 0;
    }
    #pragma unroll
    for(int j=0;j<8;++j){
      float v = bf2f(tmp[j]) * sb[k8+j] + sb[128+k8+j];
      tmp[j] = f2bf(fmaxf(v, 0.f));
    }
    *(uint4*)(act + row*136 + k8) = *(uint4*)tmp;
  }
  __syncthreads();
  int w = t >> 6, lane = t & 63;
  int ln = lane & 15, quad = lane >> 4;

  int n = w*16 + ln;
  bf16x8 B[4];
  #pragma unroll
  for(int q=0;q<4;++q)
    B[q] = *(const bf16x8*)(w2t + n*128 + q*32 + quad*8);

  f32x4 z = {0.f,0.f,0.f,0.f};
  f32x4 acc[4] = {z,z,z,z};
  #pragma unroll
  for(int q=0;q<4;++q){
    #pragma unroll
    for(int tt=0;tt<4;++tt){
      bf16x8 A = *(const bf16x8*)(act + (tt*16 + ln)*136 + q*32 + quad*8);
      acc[tt] = __builtin_amdgcn_mfma_f32_16x16x32_bf16(A, B[q], acc[tt], 0,0,0);
    }
  }
  float bb = b2[n];
  #pragma unroll
  for(int tt=0;tt<4;++tt){
    #pragma unroll
    for(int r=0;r<4;++r){
      int row = tt*16 + quad*4 + r;
      float v = fmaxf(acc[tt][r] + bb, 0.f);
      cs2[row*72 + n] = f2bf(v);
    }
  }
  __syncthreads();
  #pragma unroll
  for(int r2=0;r2<2;++r2){
    int idx = r2*256 + t;
    int row = idx >> 3, c8 = (idx & 7)*8;
    int m = n0 + row;
    if(m < N)
      *(uint4*)(h16 + (size_t)m*64 + c8) = *(const uint4*)(cs2 + row*72 + c8);
  }
}

// ---------------- fused mean-pool + dense + sigmoid (bf16 input) ----------------
__device__ __forceinline__ int lbound(const int* a, int n, int key){
  int lo = 0, hi = n;
  while(lo < hi){
    int mid = (lo + hi) >> 1;
    if(a[mid] < key) lo = mid + 1; else hi = mid;
  }
  return lo;
}

__global__ __launch_bounds__(256) void k_pool(const ushort_t* __restrict__ h16, const int* __restrict__ batch,
                                              const float* __restrict__ wd, const float* __restrict__ bd,
                                              float* __restrict__ out, int N){
  int g = blockIdx.x;
  int lo = lbound(batch, N, g);
  int hi = lbound(batch, N, g+1);
  int c = threadIdx.x & 63, w = threadIdx.x >> 6;
  float acc = 0.f;
  for(int n = lo + w; n < hi; n += 4) acc += bf2f(h16[(size_t)n*64 + c]);
  __shared__ float red[4][64];
  red[w][c] = acc;
  __syncthreads();
  if(w == 0){
    float v = red[0][c] + red[1][c] + red[2][c] + red[3][c];
    float count = (float)(hi - lo);
    v = v / fmaxf(count, 1.f) * wd[c];
    for(int off=32; off>0; off>>=1) v += __shfl_down(v, off, 64);
    if(c == 0) out[g] = 1.f / (1.f + expf(-(v + bd[0])));
  }
}

// ---------------- host ----------------

extern "C" void kernel_launch(void* const* d_in, const int* in_sizes, int n_in,
                              void* d_out, int out_size, void* d_ws, size_t ws_size,
                              hipStream_t stream){
  const float* x      = (const float*)d_in[0];
  const int*   ei     = (const int*)  d_in[1];
  const int*   batch  = (const int*)  d_in[2];
  const float* w_src  = (const float*)d_in[3];
  const float* b_src  = (const float*)d_in[4];
  const float* w_dst  = (const float*)d_in[5];
  const float* b_dst  = (const float*)d_in[6];
  const float* w_dense= (const float*)d_in[25];
  const float* b_dense= (const float*)d_in[26];
  float* out = (float*)d_out;

  const int N = in_sizes[2];
  const int E = in_sizes[1] / 2;
  const int* src = ei;
  const int* dst = ei + E;

  char* ws = (char*)d_ws;
  size_t off = 0;
  auto take = [&](size_t bytes) -> void* {
    void* p = ws + off;
    off += (bytes + 255) & ~(size_t)255;
    return p;
  };
  ushort_t* hd16 = (ushort_t*)take((size_t)N*64*2);
  ushort_t* gs16 = (ushort_t*)take((size_t)N*64*2);
  ushort_t* h1   = (ushort_t*)take((size_t)N*128*2);
  ushort_t* h16  = (ushort_t*)take((size_t)N*64*2);
  unsigned* ebuf = (unsigned*)take((size_t)E*4);
  int*      esrc = (int*)     take((size_t)E*4);
  int*      rp   = (int*)     take((size_t)(N+1)*4);
  // zero-region: bcnt[512] + ticket[64] + bnp[3*8192]  (one memset)
  int*      bcnt = (int*)     take(512*4 + 64*4 + 3*32*256*4);
  int*      ticket = bcnt + 512;
  float*    bnp  = (float*)(ticket + 64);
  int*      bbase= (int*)     take(520*4);
  int*      bcur = (int*)     take(512*4);
  float*    sb   = (float*)   take(256*4);
  ushort_t* w1t  = (ushort_t*)take(3*8192*2);
  ushort_t* w2t  = (ushort_t*)take(3*8192*2);

  const int nblk1 = (N + 31) / 32;
  const int gN64  = (N*64 + 255) / 256;
  const int NB    = (N + 255) >> 8;
  const int nchnk = (E + 4095) / 4096;
  const size_t zbytes = 512*4 + 64*4 + 3*32*256*4;

  (void)hipMemsetAsync(bcnt, 0, zbytes, stream);

  // ---- CSR by dst (bucket-local; bhist has inline last-block scan) ----
  k_bhist<<<nchnk, 256, 0, stream>>>(dst, bcnt, ticket, bbase, bcur, rp, E, NB, N, nchnk);
  k_part <<<nchnk, 256, 0, stream>>>(src, dst, bcur, ebuf, E, NB);
  k_place<<<NB,    256, 0, stream>>>(bbase, ebuf, esrc, rp, N);

  // ---- weight transpose+cast + layer-1 projections, one launch ----
  k_init<<<192 + gN64, 256, 0, stream>>>(
    (const float*)d_in[7],  (const float*)d_in[11],
    (const float*)d_in[13], (const float*)d_in[17],
    (const float*)d_in[19], (const float*)d_in[23],
    w1t, w2t,
    x, w_src, b_src, w_dst, b_dst, hd16, gs16, N);

  // ---- 3 conv layers (layers 2/3: gather source == residual == h16) ----
  const ushort_t* gs_l[3] = { gs16, h16, h16 };
  const ushort_t* xd_l[3] = { hd16, h16, h16 };
  const float invN = 1.0f / (float)N;

  for(int L=0; L<3; ++L){
    const float* b1 = (const float*)d_in[7 + 6*L + 1];
    const float* g  = (const float*)d_in[7 + 6*L + 2];
    const float* be = (const float*)d_in[7 + 6*L + 3];
    const float* b2 = (const float*)d_in[7 + 6*L + 5];
    float* bnpL = bnp + (size_t)L*32*256;

    k_emlp1<<<nblk1, 256, 0, stream>>>(gs_l[L], xd_l[L], rp, esrc, w1t + L*8192, b1, h1, bnpL, N);
    k_bnfold<<<1, 128, 0, stream>>>(bnpL, g, be, sb, invN);
    k_mlp2<<<(N+63)/64, 256, 0, stream>>>(h1, sb, w2t + L*8192, b2, h16, N);
  }

  // ---- pooled dense + sigmoid ----
  k_pool<<<512, 256, 0, stream>>>(h16, batch, w_dense, b_dense, out, N);
}

// Round 20
// 423.269 us; speedup vs baseline: 1.0684x; 1.0576x over previous
//
#include <hip/hip_runtime.h>

typedef unsigned short ushort_t;
typedef __attribute__((ext_vector_type(8))) short bf16x8;
typedef __attribute__((ext_vector_type(4))) float f32x4;
typedef __attribute__((ext_vector_type(4))) int int4v;

__device__ __forceinline__ unsigned short f2bf(float f){
  unsigned u = __float_as_uint(f);
  u = (u + 0x7FFFu + ((u >> 16) & 1u)) >> 16;     // round-to-nearest-even
  return (unsigned short)u;
}
__device__ __forceinline__ float bf2f(unsigned short h){
  return __uint_as_float(((unsigned)h) << 16);
}

// ---------------- CSR build (bucket-local) ----------------

__global__ __launch_bounds__(256) void k_bhist(const int* __restrict__ dst, int* __restrict__ bcnt,
                                               int E, int NB){
  __shared__ int l[512];
  int t = threadIdx.x;
  for(int b=t; b<512; b+=256) l[b] = 0;
  __syncthreads();
  int base = blockIdx.x*4096 + t*16;
  if(base + 16 <= E){
    #pragma unroll
    for(int r=0;r<4;++r){
      int4v d = __builtin_nontemporal_load((const int4v*)(dst + base + r*4));
      atomicAdd(&l[d.x >> 8], 1); atomicAdd(&l[d.y >> 8], 1);
      atomicAdd(&l[d.z >> 8], 1); atomicAdd(&l[d.w >> 8], 1);
    }
  } else {
    for(int i=base; i<E; ++i) atomicAdd(&l[dst[i] >> 8], 1);
  }
  __syncthreads();
  for(int b=t; b<NB; b+=256){
    int c = l[b];
    if(c) atomicAdd(&bcnt[b], c);
  }
}

__global__ __launch_bounds__(512) void k_bscan(const int* __restrict__ bcnt, int* __restrict__ bbase,
                                               int* __restrict__ bcur, int* __restrict__ rp,
                                               int NB, int N, int E){
  __shared__ int s[512];
  int t = threadIdx.x;
  int v = (t < NB) ? bcnt[t] : 0;
  s[t] = v;
  __syncthreads();
  for(int off=1; off<512; off<<=1){
    int x = 0;
    if(t >= off) x = s[t-off];
    __syncthreads();
    if(t >= off) s[t] += x;
    __syncthreads();
  }
  int excl = s[t] - v;
  if(t < NB){ bbase[t] = excl; bcur[t] = excl; }
  if(t == NB-1) bbase[NB] = excl + v;   // = E
  if(t == 0) rp[N] = E;
}

__global__ __launch_bounds__(256) void k_part(const int* __restrict__ src, const int* __restrict__ dst,
                                              int* __restrict__ bcur, unsigned* __restrict__ ebuf,
                                              int E, int NB){
  __shared__ int lcnt[512];
  __shared__ int lbase[512];
  int t = threadIdx.x;
  int base = blockIdx.x*4096 + t*16;
  for(int b=t; b<NB; b+=256) lcnt[b] = 0;
  __syncthreads();

  int srcv[16], dstv[16];
  if(base + 16 <= E){
    #pragma unroll
    for(int r=0;r<4;++r){
      *(int4v*)(dstv + r*4) = __builtin_nontemporal_load((const int4v*)(dst + base + r*4));
      *(int4v*)(srcv + r*4) = __builtin_nontemporal_load((const int4v*)(src + base + r*4));
    }
  } else {
    #pragma unroll
    for(int k=0;k<16;++k){
      int i = base + k;
      if(i < E){ dstv[k] = dst[i]; srcv[k] = src[i]; }
      else dstv[k] = -1;
    }
  }
  #pragma unroll
  for(int r=0;r<16;++r)
    if(dstv[r] >= 0) atomicAdd(&lcnt[dstv[r] >> 8], 1);
  __syncthreads();
  for(int b=t; b<NB; b+=256){
    int c = lcnt[b];
    lbase[b] = c ? atomicAdd(&bcur[b], c) : 0;
    lcnt[b] = 0;
  }
  __syncthreads();
  #pragma unroll
  for(int r=0;r<16;++r){
    if(dstv[r] >= 0){
      int b = dstv[r] >> 8;
      int p = lbase[b] + atomicAdd(&lcnt[b], 1);
      ebuf[p] = (((unsigned)dstv[r] & 255u) << 17) | (unsigned)srcv[r];
    }
  }
}

__global__ __launch_bounds__(256) void k_place(const int* __restrict__ bbase, const unsigned* __restrict__ ebuf,
                                               int* __restrict__ esrc, int* __restrict__ rp, int N){
  __shared__ int lcnt[256];
  __shared__ int sc[256];
  __shared__ int lcur[256];
  int t = threadIdx.x;
  int b = blockIdx.x;
  int n0 = b << 8;
  int e0 = bbase[b], e1 = bbase[b+1];
  lcnt[t] = 0;
  __syncthreads();
  for(int i = e0 + t; i < e1; i += 256)
    atomicAdd(&lcnt[ebuf[i] >> 17], 1);
  __syncthreads();
  int v = lcnt[t];
  sc[t] = v;
  __syncthreads();
  for(int off=1; off<256; off<<=1){
    int x = 0;
    if(t >= off) x = sc[t-off];
    __syncthreads();
    if(t >= off) sc[t] += x;
    __syncthreads();
  }
  int rpv = e0 + sc[t] - v;
  if(n0 + t < N) rp[n0 + t] = rpv;
  lcur[t] = rpv;
  __syncthreads();
  for(int i = e0 + t; i < e1; i += 256){
    unsigned w = ebuf[i];
    int dl = (int)(w >> 17);
    int p = atomicAdd(&lcur[dl], 1);
    esrc[p] = (int)(w & 0x1FFFFu);
  }
}

// ---------------- weight transpose+cast for all 3 layers ----------------
__global__ __launch_bounds__(256) void k_wconv(const float* __restrict__ w1a, const float* __restrict__ w2a,
                                               const float* __restrict__ w1b, const float* __restrict__ w2b,
                                               const float* __restrict__ w1c, const float* __restrict__ w2c,
                                               ushort_t* __restrict__ w1t, ushort_t* __restrict__ w2t){
  int L = blockIdx.x >> 6;
  const float* w1 = (L==0) ? w1a : (L==1) ? w1b : w1c;
  const float* w2 = (L==0) ? w2a : (L==1) ? w2b : w2c;
  int t = (blockIdx.x & 63)*256 + threadIdx.x;
  if(t < 8192){
    int n = t >> 6, k = t & 63;
    w1t[L*8192 + n*64 + k] = f2bf(w1[k*128 + n]);
  } else {
    int i = t - 8192;
    int n = i >> 7, k = i & 127;
    w2t[L*8192 + n*128 + k] = f2bf(w2[k*64 + n]);
  }
}

// ---------------- layer 0 input projections ----------------
__global__ __launch_bounds__(256) void k_proj(const float* __restrict__ x,
                                              const float* __restrict__ ws, const float* __restrict__ bs,
                                              const float* __restrict__ wd, const float* __restrict__ bd,
                                              ushort_t* __restrict__ hd16, ushort_t* __restrict__ gs16, int N){
  int gid = blockIdx.x*256 + threadIdx.x;
  int n = gid >> 6, c = gid & 63;
  if(n >= N) return;
  float as = bs[c], ad = bd[c];
  const float* xr = x + (size_t)n*9;
  #pragma unroll
  for(int k=0;k<9;++k){
    float xv = xr[k];
    as += xv * ws[k*64 + c];
    ad += xv * wd[k*64 + c];
  }
  hd16[(size_t)n*64 + c] = f2bf(ad);
  gs16[(size_t)n*64 + c] = f2bf(fmaxf(as, 0.f));
}

// ---------------- fused edge + MLP1: h1 = (softmax-agg + xd) @ w1 + b1 ----------------
// Eps-folding (exact): exp(v+eps) = e^eps * exp(v); the constant cancels in the
// softmax ratio, so S += exp(v), T += exp(v)*v, aggr = (T + eps*S)/(S + 1e-16).
__global__ __launch_bounds__(256) void k_emlp1(const ushort_t* __restrict__ gs, const ushort_t* __restrict__ xd16,
                                               const int* __restrict__ rp, const int* __restrict__ es,
                                               const ushort_t* __restrict__ w1t, const float* __restrict__ b1,
                                               ushort_t* __restrict__ h1, float* __restrict__ bnp, int N){
  __shared__ ushort_t yt[32*72];       // y tile
  __shared__ ushort_t cs[32*136];      // C staging
  int t = threadIdx.x;
  int w = t >> 6, lane = t & 63;
  int nbase = blockIdx.x * 32;

  // ---- edge phase: wave w aggregates nodes nbase + w*8 .. +7 ----
  const ushort_t* gl = gs + lane;
  for(int i=0;i<8;++i){
    int nl = w*8 + i;
    int n = nbase + nl;
    float aggr = 0.f;
    if(n < N){
      int beg = __builtin_amdgcn_readfirstlane(rp[n]);
      int end = __builtin_amdgcn_readfirstlane(rp[n+1]);
      float S[8], T[8];
      #pragma unroll
      for(int j=0;j<8;++j){ S[j]=0.f; T[j]=0.f; }
      int nfull = beg + ((end - beg) & ~7);
      int base = beg;
      for(; base < nfull; base += 8){       // interior: no per-element mask
        float g[8];
        #pragma unroll
        for(int j=0;j<8;++j){
          int idx = __builtin_amdgcn_readfirstlane(es[base+j]);
          g[j] = bf2f(gl[(size_t)idx*64]);
        }
        #pragma unroll
        for(int j=0;j<8;++j){
          float p = __expf(g[j]);
          S[j] += p; T[j] += p*g[j];
        }
      }
      if(base < end){                        // single masked tail group
        float g[8];
        #pragma unroll
        for(int j=0;j<8;++j){
          int e = base + j;
          int idx = __builtin_amdgcn_readfirstlane(es[e < end ? e : end-1]);
          g[j] = bf2f(gl[(size_t)idx*64]);
        }
        #pragma unroll
        for(int j=0;j<8;++j){
          float p = (base + j < end) ? __expf(g[j]) : 0.f;
          S[j] += p; T[j] += p*g[j];
        }
      }
      float Ss = ((S[0]+S[1])+(S[2]+S[3])) + ((S[4]+S[5])+(S[6]+S[7]));
      float Ts = ((T[0]+T[1])+(T[2]+T[3])) + ((T[4]+T[5])+(T[6]+T[7]));
      aggr = (Ts + 1e-7f*Ss)/(Ss + 1e-16f) + bf2f(xd16[(size_t)n*64 + lane]);
    }
    yt[nl*72 + lane] = f2bf(aggr);
  }
  __syncthreads();

  // ---- MFMA phase (mlp1): A from LDS y-tile ----
  int ln = lane & 15, quad = lane >> 4;
  bf16x8 B[2][2];
  #pragma unroll
  for(int c=0;c<2;++c){
    int n = (2*w+c)*16 + ln;
    #pragma unroll
    for(int q=0;q<2;++q)
      B[c][q] = *(const bf16x8*)(w1t + n*64 + q*32 + quad*8);
  }

  f32x4 z = {0.f,0.f,0.f,0.f};
  f32x4 acc[2][2] = {{z,z},{z,z}};
  #pragma unroll
  for(int q=0;q<2;++q){
    #pragma unroll
    for(int tt=0;tt<2;++tt){
      bf16x8 A = *(const bf16x8*)(yt + (tt*16 + ln)*72 + q*32 + quad*8);
      #pragma unroll
      for(int c=0;c<2;++c)
        acc[tt][c] = __builtin_amdgcn_mfma_f32_16x16x32_bf16(A, B[c][q], acc[tt][c], 0,0,0);
    }
  }

  float s[2] = {0.f, 0.f}, qq[2] = {0.f, 0.f};
  #pragma unroll
  for(int c=0;c<2;++c){
    int n = (2*w+c)*16 + ln;
    float bb = b1[n];
    #pragma unroll
    for(int tt=0;tt<2;++tt){
      #pragma unroll
      for(int r=0;r<4;++r){
        int row = tt*16 + quad*4 + r;
        float v = acc[tt][c][r] + bb;
        bool ok = (nbase + row) < N;
        s[c]  += ok ? v   : 0.f;
        qq[c] += ok ? v*v : 0.f;
        cs[row*136 + n] = f2bf(v);
      }
    }
  }
  {
    float* slice = bnp + (size_t)(blockIdx.x & 31)*256;
    #pragma unroll
    for(int c=0;c<2;++c){
      float vs = s[c], vq = qq[c];
      vs += __shfl_down(vs, 32, 64); vs += __shfl_down(vs, 16, 64);
      vq += __shfl_down(vq, 32, 64); vq += __shfl_down(vq, 16, 64);
      if(quad == 0){
        int col = (2*w+c)*16 + ln;
        atomicAdd(&slice[col], vs);
        atomicAdd(&slice[128+col], vq);
      }
    }
  }
  __syncthreads();
  #pragma unroll
  for(int r2=0;r2<2;++r2){
    int idx = r2*256 + t;
    int row = idx >> 4, c8 = (idx & 15)*8;
    int m = nbase + row;
    if(m < N)
      *(uint4*)(h1 + (size_t)m*128 + c8) = *(const uint4*)(cs + row*136 + c8);
  }
}

// fold BN stats from this layer's bnp[32][256] slice -> sb (scale/bias)
__global__ __launch_bounds__(128) void k_bnfold(const float* __restrict__ bnp, const float* __restrict__ g,
                                                const float* __restrict__ be, float* __restrict__ sb, float invN){
  int j = threadIdx.x;
  float s = 0.f, q = 0.f;
  for(int b=0;b<32;++b){ s += bnp[b*256 + j]; q += bnp[b*256 + 128 + j]; }
  float mu = s*invN;
  float var = q*invN - mu*mu;
  float sc = g[j] * rsqrtf(var + 1e-5f);
  sb[j] = sc;
  sb[128+j] = be[j] - mu*sc;
}

// ---------------- MLP part 2 (MFMA): h16 = relu(relu(bn(h1)) @ w2 + b2) ----------------
__global__ __launch_bounds__(256) void k_mlp2(const ushort_t* __restrict__ h1, const float* __restrict__ sb,
                                              const ushort_t* __restrict__ w2t, const float* __restrict__ b2,
                                              ushort_t* __restrict__ h16, int N){
  __shared__ ushort_t act[64*136];
  __shared__ ushort_t cs2[64*72];
  int t = threadIdx.x;
  int n0 = blockIdx.x*64;
  #pragma unroll
  for(int r=0;r<4;++r){
    int idx = r*256 + t;
    int row = idx >> 4, k8 = (idx & 15)*8;
    int n = n0 + row;
    ushort_t tmp[8];
    if(n < N){
      *(uint4*)tmp = *(const uint4*)(h1 + (size_t)n*128 + k8);
    } else {
      #pragma unroll
      for(int j=0;j<8;++j) tmp[j] = 0;
    }
    #pragma unroll
    for(int j=0;j<8;++j){
      float v = bf2f(tmp[j]) * sb[k8+j] + sb[128+k8+j];
      tmp[j] = f2bf(fmaxf(v, 0.f));
    }
    *(uint4*)(act + row*136 + k8) = *(uint4*)tmp;
  }
  __syncthreads();
  int w = t >> 6, lane = t & 63;
  int ln = lane & 15, quad = lane >> 4;

  int n = w*16 + ln;
  bf16x8 B[4];
  #pragma unroll
  for(int q=0;q<4;++q)
    B[q] = *(const bf16x8*)(w2t + n*128 + q*32 + quad*8);

  f32x4 z = {0.f,0.f,0.f,0.f};
  f32x4 acc[4] = {z,z,z,z};
  #pragma unroll
  for(int q=0;q<4;++q){
    #pragma unroll
    for(int tt=0;tt<4;++tt){
      bf16x8 A = *(const bf16x8*)(act + (tt*16 + ln)*136 + q*32 + quad*8);
      acc[tt] = __builtin_amdgcn_mfma_f32_16x16x32_bf16(A, B[q], acc[tt], 0,0,0);
    }
  }
  float bb = b2[n];
  #pragma unroll
  for(int tt=0;tt<4;++tt){
    #pragma unroll
    for(int r=0;r<4;++r){
      int row = tt*16 + quad*4 + r;
      float v = fmaxf(acc[tt][r] + bb, 0.f);
      cs2[row*72 + n] = f2bf(v);
    }
  }
  __syncthreads();
  #pragma unroll
  for(int r2=0;r2<2;++r2){
    int idx = r2*256 + t;
    int row = idx >> 3, c8 = (idx & 7)*8;
    int m = n0 + row;
    if(m < N)
      *(uint4*)(h16 + (size_t)m*64 + c8) = *(const uint4*)(cs2 + row*72 + c8);
  }
}

// ---------------- fused mean-pool + dense + sigmoid (bf16 input) ----------------
__device__ __forceinline__ int lbound(const int* a, int n, int key){
  int lo = 0, hi = n;
  while(lo < hi){
    int mid = (lo + hi) >> 1;
    if(a[mid] < key) lo = mid + 1; else hi = mid;
  }
  return lo;
}

__global__ __launch_bounds__(256) void k_pool(const ushort_t* __restrict__ h16, const int* __restrict__ batch,
                                              const float* __restrict__ wd, const float* __restrict__ bd,
                                              float* __restrict__ out, int N){
  int g = blockIdx.x;
  int lo = lbound(batch, N, g);
  int hi = lbound(batch, N, g+1);
  int c = threadIdx.x & 63, w = threadIdx.x >> 6;
  float acc = 0.f;
  for(int n = lo + w; n < hi; n += 4) acc += bf2f(h16[(size_t)n*64 + c]);
  __shared__ float red[4][64];
  red[w][c] = acc;
  __syncthreads();
  if(w == 0){
    float v = red[0][c] + red[1][c] + red[2][c] + red[3][c];
    float count = (float)(hi - lo);
    v = v / fmaxf(count, 1.f) * wd[c];
    for(int off=32; off>0; off>>=1) v += __shfl_down(v, off, 64);
    if(c == 0) out[g] = 1.f / (1.f + expf(-(v + bd[0])));
  }
}

// ---------------- host ----------------

extern "C" void kernel_launch(void* const* d_in, const int* in_sizes, int n_in,
                              void* d_out, int out_size, void* d_ws, size_t ws_size,
                              hipStream_t stream){
  const float* x      = (const float*)d_in[0];
  const int*   ei     = (const int*)  d_in[1];
  const int*   batch  = (const int*)  d_in[2];
  const float* w_src  = (const float*)d_in[3];
  const float* b_src  = (const float*)d_in[4];
  const float* w_dst  = (const float*)d_in[5];
  const float* b_dst  = (const float*)d_in[6];
  const float* w_dense= (const float*)d_in[25];
  const float* b_dense= (const float*)d_in[26];
  float* out = (float*)d_out;

  const int N = in_sizes[2];
  const int E = in_sizes[1] / 2;
  const int* src = ei;
  const int* dst = ei + E;

  char* ws = (char*)d_ws;
  size_t off = 0;
  auto take = [&](size_t bytes) -> void* {
    void* p = ws + off;
    off += (bytes + 255) & ~(size_t)255;
    return p;
  };
  ushort_t* hd16 = (ushort_t*)take((size_t)N*64*2);
  ushort_t* gs16 = (ushort_t*)take((size_t)N*64*2);
  ushort_t* h1   = (ushort_t*)take((size_t)N*128*2);
  ushort_t* h16  = (ushort_t*)take((size_t)N*64*2);
  unsigned* ebuf = (unsigned*)take((size_t)E*4);
  int*      esrc = (int*)     take((size_t)E*4);
  int*      rp   = (int*)     take((size_t)(N+1)*4);
  // zero-region: bcnt[512] + bnp[3*8192]  (one memset)
  int*      bcnt = (int*)     take(512*4 + 3*32*256*4);
  float*    bnp  = (float*)(bcnt + 512);
  int*      bbase= (int*)     take(520*4);
  int*      bcur = (int*)     take(512*4);
  float*    sb   = (float*)   take(256*4);
  ushort_t* w1t  = (ushort_t*)take(3*8192*2);
  ushort_t* w2t  = (ushort_t*)take(3*8192*2);

  const int nblk1 = (N + 31) / 32;
  const int gN64  = (N*64 + 255) / 256;
  const int NB    = (N + 255) >> 8;
  const int nchnk = (E + 4095) / 4096;
  const size_t zbytes = 512*4 + 3*32*256*4;

  (void)hipMemsetAsync(bcnt, 0, zbytes, stream);

  // ---- weight transpose+cast, all 3 layers ----
  k_wconv<<<192, 256, 0, stream>>>(
    (const float*)d_in[7],  (const float*)d_in[11],
    (const float*)d_in[13], (const float*)d_in[17],
    (const float*)d_in[19], (const float*)d_in[23],
    w1t, w2t);

  // ---- CSR by dst (bucket-local build) ----
  k_bhist<<<nchnk, 256, 0, stream>>>(dst, bcnt, E, NB);
  k_bscan<<<1,     512, 0, stream>>>(bcnt, bbase, bcur, rp, NB, N, E);
  k_part <<<nchnk, 256, 0, stream>>>(src, dst, bcur, ebuf, E, NB);
  k_place<<<NB,    256, 0, stream>>>(bbase, ebuf, esrc, rp, N);

  // ---- layer-1 input projections ----
  k_proj<<<gN64, 256, 0, stream>>>(x, w_src, b_src, w_dst, b_dst, hd16, gs16, N);

  // ---- 3 conv layers (layers 2/3: gather source == residual == h16) ----
  const ushort_t* gs_l[3] = { gs16, h16, h16 };
  const ushort_t* xd_l[3] = { hd16, h16, h16 };
  const float invN = 1.0f / (float)N;

  for(int L=0; L<3; ++L){
    const float* b1 = (const float*)d_in[7 + 6*L + 1];
    const float* g  = (const float*)d_in[7 + 6*L + 2];
    const float* be = (const float*)d_in[7 + 6*L + 3];
    const float* b2 = (const float*)d_in[7 + 6*L + 5];
    float* bnpL = bnp + (size_t)L*32*256;

    k_emlp1<<<nblk1, 256, 0, stream>>>(gs_l[L], xd_l[L], rp, esrc, w1t + L*8192, b1, h1, bnpL, N);
    k_bnfold<<<1, 128, 0, stream>>>(bnpL, g, be, sb, invN);
    k_mlp2<<<(N+63)/64, 256, 0, stream>>>(h1, sb, w2t + L*8192, b2, h16, N);
  }

  // ---- pooled dense + sigmoid ----
  k_pool<<<512, 256, 0, stream>>>(h16, batch, w_dense, b_dense, out, N);
}